// Round 14
// baseline (2039.297 us; speedup 1.0000x reference)
//
#include <hip/hip_runtime.h>

#define N_NODES 100000
#define N_EDGES 1600000
#define D 128      // D_IN == D_HID
#define D_OUT 64

// r14: CSR phase DELETED. Aggregation runs directly over the bucketed edge
// list into an LDS f32 accumulator (exclusive 128-node ownership per block —
// honors the r1/r10 rule with LDS instead of csrp). Removes csr_build, csrp
// (25.6MB), dcount, sentinels, MAXDEG, and agg's shuffle machinery.
// Split rules kept: histogram multisplit (r12), 500 blocks (r8), no re-scan
// (r11), LDS slot cursors (r1/r10).
#define NBUCK 782          // buckets of 128 nodes
#define BSHIFT 7
#define BMASK 127
#define BCAP  3072         // avg 2046 edges/bucket, ~10 sigma slack
#define NSPL 500
#define CHUNK 3200         // 500*3200 = 1.6M exact
#define GEMM_BLOCKS 1563   // ceil(100000/64)
#define ASTR 65            // LDS acc row stride (dwords): 65%32=1 -> dloc spreads banks

typedef __attribute__((ext_vector_type(8))) short short8;   // 8 bf16 (4 VGPRs)
typedef __attribute__((ext_vector_type(4))) float floatx4;  // MFMA C/D
typedef __attribute__((ext_vector_type(2))) float floatx2;
typedef __attribute__((ext_vector_type(4))) unsigned uint32x4;

__device__ inline unsigned short f2bf(float f) {   // RNE f32 -> bf16 (cold paths)
    unsigned u = __builtin_bit_cast(unsigned, f);
    u = (u + 0x7fffu + ((u >> 16) & 1u)) >> 16;
    return (unsigned short)u;
}
__device__ inline float bf2f(unsigned u16) {
    return __builtin_bit_cast(float, u16 << 16);
}
// HW packed RNE f32x2 -> bf16x2 (1 instr vs ~8 scalar VALU ops)
__device__ inline unsigned cvt_pk_bf16(float lo, float hi) {
    unsigned r;
    asm("v_cvt_pk_bf16_f32 %0, %1, %2" : "=v"(r) : "v"(lo), "v"(hi));
    return r;
}

// ---- pack W = [Wa | Wb] (N-concat, K=128) into MFMA B-frag order ----
// KPERM: permute K-rows to consume an interleave-stored A (gemm ILV=1 output):
// packed K-position k holds original row ((k&7)<<4)|(k>>3).
template<bool KPERM>
__device__ inline void pack_ncat(const float* __restrict__ Wa, const float* __restrict__ Wb,
                                 int ncA, int ncB, unsigned short* __restrict__ out, int t) {
    int nnt = (ncA + ncB) >> 4;
    int lane = t & 63;
    int nt = (t >> 6) % nnt;
    int kt = t / (64 * nnt);                 // 0..3 (K=128)
    int col = nt * 16 + (lane & 15);
    int k0 = kt * 32 + ((lane >> 4) << 3);
    const float* W = (col < ncA) ? Wa : Wb;
    int nc = (col < ncA) ? ncA : ncB;
    int c  = (col < ncA) ? col : col - ncA;
    unsigned short* dstp = out + (size_t)((kt * nnt + nt) * 64 + lane) * 8;
    #pragma unroll
    for (int j = 0; j < 8; ++j) {
        int k = k0 + j;
        int kr = KPERM ? (((k & 7) << 4) | (k >> 3)) : k;
        dstp[j] = f2bf(W[(size_t)kr * nc + c]);
    }
}

// ------- launch 1: histogram multisplit into 782 buckets ∪ weight pack ----------
__global__ __launch_bounds__(256) void split_pack(
        const int* __restrict__ src, const int* __restrict__ dst,
        int* __restrict__ gcur, int* __restrict__ bucketbuf,
        const float* __restrict__ Ws1, const float* __restrict__ Wn1,
        const float* __restrict__ Ws2, const float* __restrict__ Wn2,
        unsigned short* __restrict__ Wp1, unsigned short* __restrict__ Wp2) {
    __shared__ int cnt[NBUCK];
    __shared__ int base_s[NBUCK];
    __shared__ int dstc[CHUNK];    // cache dst chunk: read HBM once, not twice
    const int tid = threadIdx.x;
    const int b = blockIdx.x;
    if (b < NSPL) {
        const int e0 = b * CHUNK;
        for (int i = tid; i < NBUCK; i += 256) cnt[i] = 0;
        __syncthreads();
        for (int i = tid; i < CHUNK; i += 256) {
            int d = __builtin_nontemporal_load(dst + e0 + i);
            dstc[i] = d;
            atomicAdd(&cnt[d >> BSHIFT], 1);
        }
        __syncthreads();
        for (int i = tid; i < NBUCK; i += 256) {
            int c = cnt[i];
            base_s[i] = c ? atomicAdd(&gcur[i], c) : 0;
            cnt[i] = 0;   // reuse as per-block write cursor
        }
        __syncthreads();
        for (int i = tid; i < CHUNK; i += 256) {
            int d = dstc[i];
            int s = __builtin_nontemporal_load(src + e0 + i);
            int bk = d >> BSHIFT;
            int p = base_s[bk] + atomicAdd(&cnt[bk], 1);
            if (p < BCAP)   // statically impossible overflow; safety net
                bucketbuf[bk * BCAP + p] = ((d & BMASK) << 17) | s;
        }
    } else {
        int sub = b - NSPL;
        if (sub < 16) pack_ncat<false>(Ws1, Wn1, D, D, Wp1, sub * 256 + tid);
        else          pack_ncat<true >(Ws2, Wn2, D_OUT, D_OUT, Wp2, (sub - 16) * 256 + tid);
    }
}

// --------------- shared GEMM body: [self+bias | nbr] = A @ [Ws | Wn], K=128 -----
// ILV=1 (layer 1, NTA=NTB=8): store position m*8+nt <- col nt*16+m; one 16B bf16
//   + one 8B fp8 store per row per lane. Wp2 is K-row-permuted to consume it.
// ILV=2 (layer 2, NTA=NTB=4): store position m*4+nt <- col nt*16+m; one 16B f32
//   + one 4B fp8 store. bagg<L2> un-permutes at its final coalesced write.
template<int NTA, int NTB, bool AF32, int ILV>
__device__ inline void gemm_body(int bid,
        const void* __restrict__ A, const unsigned short* __restrict__ Wp,
        const float* __restrict__ bias, void* __restrict__ OutA,
        unsigned char* __restrict__ OutB, int tid)
{
    const int NT = NTA + NTB;
    const int wave = tid >> 6;
    const int lane = tid & 63;
    const int q = lane >> 4, m = lane & 15;

    int row = bid * 64 + wave * 16 + m;
    int rowc = (row < N_NODES) ? row : (N_NODES - 1);

    floatx4 acc[NT];
    #pragma unroll
    for (int nt = 0; nt < NT; ++nt) acc[nt] = (floatx4){0.f, 0.f, 0.f, 0.f};

    #pragma unroll
    for (int kt = 0; kt < 4; ++kt) {
        short8 af;
        if (AF32) {
            const float* xr = (const float*)A + (size_t)rowc * D + kt * 32 + q * 8;
            float4 f0 = *(const float4*)xr;
            float4 f1 = *(const float4*)(xr + 4);
            uint32x4 t;
            t[0] = cvt_pk_bf16(f0.x, f0.y);
            t[1] = cvt_pk_bf16(f0.z, f0.w);
            t[2] = cvt_pk_bf16(f1.x, f1.y);
            t[3] = cvt_pk_bf16(f1.z, f1.w);
            af = __builtin_bit_cast(short8, t);
        } else {
            af = *(const short8*)((const unsigned short*)A +
                                  (size_t)rowc * D + kt * 32 + q * 8);
        }
        #pragma unroll
        for (int nt = 0; nt < NT; ++nt) {
            short8 bf = *(const short8*)(Wp + (size_t)((kt * NT + nt) * 64 + lane) * 8);
            acc[nt] = __builtin_amdgcn_mfma_f32_16x16x32_bf16(af, bf, acc[nt], 0, 0, 0);
        }
    }

    const int orow_base = bid * 64 + wave * 16 + q * 4;
    if (ILV == 1) {
        float bv[8];
        #pragma unroll
        for (int nt = 0; nt < 8; ++nt) bv[nt] = bias[nt * 16 + m];
        #pragma unroll
        for (int i = 0; i < 4; ++i) {
            int orow = orow_base + i;
            if (orow < N_NODES) {
                uint32x4 pv;
                #pragma unroll
                for (int t = 0; t < 4; ++t)
                    pv[t] = cvt_pk_bf16(acc[2 * t][i]     + bv[2 * t],
                                        acc[2 * t + 1][i] + bv[2 * t + 1]);
                *(uint32x4*)((unsigned short*)OutA + (size_t)orow * 128 + m * 8) = pv;
                int pk0 = __builtin_amdgcn_cvt_pk_fp8_f32(acc[8][i],  acc[9][i],  0,   false);
                pk0     = __builtin_amdgcn_cvt_pk_fp8_f32(acc[10][i], acc[11][i], pk0, true);
                int pk1 = __builtin_amdgcn_cvt_pk_fp8_f32(acc[12][i], acc[13][i], 0,   false);
                pk1     = __builtin_amdgcn_cvt_pk_fp8_f32(acc[14][i], acc[15][i], pk1, true);
                uint2 v8; v8.x = (unsigned)pk0; v8.y = (unsigned)pk1;
                *(uint2*)(OutB + (size_t)orow * 128 + m * 8) = v8;
            }
        }
    } else {  // ILV == 2
        float bv[4];
        #pragma unroll
        for (int nt = 0; nt < 4; ++nt) bv[nt] = bias[nt * 16 + m];
        #pragma unroll
        for (int i = 0; i < 4; ++i) {
            int orow = orow_base + i;
            if (orow < N_NODES) {
                float4 o;
                o.x = acc[0][i] + bv[0]; o.y = acc[1][i] + bv[1];
                o.z = acc[2][i] + bv[2]; o.w = acc[3][i] + bv[3];
                *(float4*)((float*)OutA + (size_t)orow * 64 + m * 4) = o;
                int pk = __builtin_amdgcn_cvt_pk_fp8_f32(acc[4][i], acc[5][i], 0,  false);
                pk     = __builtin_amdgcn_cvt_pk_fp8_f32(acc[6][i], acc[7][i], pk, true);
                *(unsigned*)(OutB + (size_t)orow * 64 + m * 4) = (unsigned)pk;
            }
        }
    }
}

__global__ __launch_bounds__(256) void gemm1(
        const float* __restrict__ x, const unsigned short* __restrict__ Wp1,
        const float* __restrict__ b1, unsigned short* __restrict__ xs,
        unsigned char* __restrict__ y8)
{
    gemm_body<8, 8, true, 1>(blockIdx.x, x, Wp1, b1, xs, y8, threadIdx.x);
}

__global__ __launch_bounds__(256) void gemm2(
        const unsigned short* __restrict__ h, const unsigned short* __restrict__ Wp2,
        const float* __restrict__ b2, float* __restrict__ tmp,
        unsigned char* __restrict__ z8)
{
    gemm_body<4, 4, false, 2>(blockIdx.x, h, Wp2, b2, tmp, z8, threadIdx.x);
}

// -------- bucket aggregation: LDS f32 accumulator, straight from bucketbuf ------
// Block owns 128 nodes (one bucket; L1: one 64-col half of it). Per edge:
// 16 lanes broadcast-load the packed entry, gather 4B of the fp8 feature row,
// accumulate 4 floats into acc[dloc] via LDS float atomics. deg counted in
// lcnt. Epilogue: mean + self + (ReLU/cvt) + coalesced store.
// L1: feat=y8 (128B rows), grid 2*NBUCK (col halves), self=xs bf16, out=h bf16.
// L2: feat=z8 (64B rows), grid NBUCK, self=tmp f32 (pi2), out f32 (identity).
template<bool L1>
__global__ __launch_bounds__(256) void bucket_agg(
        const unsigned char* __restrict__ feat,
        const int* __restrict__ gcur, const int* __restrict__ bucketbuf,
        const void* __restrict__ self, void* __restrict__ out)
{
    __shared__ float acc[128 * ASTR];   // 33.3 KB
    __shared__ int lcnt[128];
    const int tid = threadIdx.x;
    const int FSH = L1 ? 7 : 6;         // log2(feature row bytes)
    int b, off;
    if (L1) { b = blockIdx.x >> 1; off = (blockIdx.x & 1) << 6; }  // byte/col offset
    else    { b = blockIdx.x;      off = 0; }

    for (int i = tid; i < 128 * ASTR; i += 256) acc[i] = 0.f;
    if (tid < 128) lcnt[tid] = 0;
    __syncthreads();

    int m = gcur[b]; if (m > BCAP) m = BCAP;
    const int* __restrict__ buf = bucketbuf + b * BCAP;
    const int l  = tid & 15;            // col chunk (4 fp8 cols)
    const int eg = tid >> 4;            // edge slot within 16-edge group

    int base = 0;
    for (; base + 64 <= m; base += 64) {     // 4 edges in flight per thread
        int v[4]; unsigned w[4];
        #pragma unroll
        for (int u = 0; u < 4; ++u) v[u] = buf[base + u * 16 + eg];
        #pragma unroll
        for (int u = 0; u < 4; ++u) {
            int s = v[u] & 0x1FFFF;
            w[u] = *(const unsigned*)(feat + ((size_t)s << FSH) + off + (l << 2));
        }
        #pragma unroll
        for (int u = 0; u < 4; ++u) {
            int dloc = (v[u] >> 17) & BMASK;
            floatx2 lo = __builtin_amdgcn_cvt_pk_f32_fp8(w[u], false);
            floatx2 hi = __builtin_amdgcn_cvt_pk_f32_fp8(w[u], true);
            float* ap = &acc[dloc * ASTR + (l << 2)];
            unsafeAtomicAdd(ap + 0, lo.x);
            unsafeAtomicAdd(ap + 1, lo.y);
            unsafeAtomicAdd(ap + 2, hi.x);
            unsafeAtomicAdd(ap + 3, hi.y);
            if (l == 0) atomicAdd(&lcnt[dloc], 1);
        }
    }
    for (int eid = base + eg; eid < m; eid += 16) {   // tail
        int v = buf[eid];
        int dloc = (v >> 17) & BMASK, s = v & 0x1FFFF;
        unsigned w = *(const unsigned*)(feat + ((size_t)s << FSH) + off + (l << 2));
        floatx2 lo = __builtin_amdgcn_cvt_pk_f32_fp8(w, false);
        floatx2 hi = __builtin_amdgcn_cvt_pk_f32_fp8(w, true);
        float* ap = &acc[dloc * ASTR + (l << 2)];
        unsafeAtomicAdd(ap + 0, lo.x);
        unsafeAtomicAdd(ap + 1, lo.y);
        unsafeAtomicAdd(ap + 2, hi.x);
        unsafeAtomicAdd(ap + 3, hi.y);
        if (l == 0) atomicAdd(&lcnt[dloc], 1);
    }
    __syncthreads();

    if (L1) {
        // positional: h[node*128 + off + c] = relu(xs[same] + mean), bf16
        for (int idx = tid; idx < 128 * 8; idx += 256) {
            int n = idx >> 3, oc = (idx & 7) << 3;        // 8 cols per item
            int node = (b << 7) + n;
            if (node < N_NODES) {
                int c = lcnt[n];
                float invd = (c > 0) ? 1.0f / (float)c : 1.0f;
                const float* ap = &acc[n * ASTR + oc];
                uint32x4 sv = *(const uint32x4*)((const unsigned short*)self +
                                                 ((size_t)node << 7) + off + oc);
                uint32x4 pv;
                #pragma unroll
                for (int t = 0; t < 4; ++t) {
                    float h0 = bf2f(sv[t] & 0xffffu) + ap[2 * t] * invd;
                    float h1 = bf2f(sv[t] >> 16)     + ap[2 * t + 1] * invd;
                    pv[t] = cvt_pk_bf16(fmaxf(h0, 0.f), fmaxf(h1, 0.f));
                }
                *(uint32x4*)((unsigned short*)out + ((size_t)node << 7) + off + oc) = pv;
            }
        }
    } else {
        // un-permute pi2 at the store: col = (p&3)*16 + p>>2; contiguous f32x4 out
        for (int idx = tid; idx < 128 * 16; idx += 256) {
            int n = idx >> 4, g = idx & 15;               // 4 cols per item
            int node = (b << 7) + n;
            if (node < N_NODES) {
                int c = lcnt[n];
                float invd = (c > 0) ? 1.0f / (float)c : 1.0f;
                float4 o;
                #pragma unroll
                for (int j = 0; j < 4; ++j) {
                    int col = (g << 2) + j;
                    int p = ((col & 15) << 2) + (col >> 4);   // positional index
                    float sv = ((const float*)self)[(size_t)node * 64 + p];
                    o[j] = sv + acc[n * ASTR + p] * invd;
                }
                *(float4*)((float*)out + (size_t)node * 64 + (g << 2)) = o;
            }
        }
    }
}

extern "C" void kernel_launch(void* const* d_in, const int* in_sizes, int n_in,
                              void* d_out, int out_size, void* d_ws, size_t ws_size,
                              hipStream_t stream) {
    const float* x   = (const float*)d_in[0];
    const int*   src = (const int*)d_in[1];
    const int*   dst = (const int*)d_in[2];
    const float* Ws1 = (const float*)d_in[3];
    const float* Wn1 = (const float*)d_in[4];
    const float* b1  = (const float*)d_in[5];
    const float* Ws2 = (const float*)d_in[6];
    const float* Wn2 = (const float*)d_in[7];
    const float* b2  = (const float*)d_in[8];
    float* out = (float*)d_out;

    const size_t nd = (size_t)N_NODES * D;   // 12.8M elements
    unsigned short* h   = (unsigned short*)d_ws;          // bf16 hidden   25.6 MB
    unsigned short* xs  = h + nd;                         // bf16 self (L1) 25.6 MB
    float*          tmp = (float*)xs;                     // f32 self (L2), aliased
    unsigned char*  y8  = (unsigned char*)(xs + nd);      // fp8 y         12.8 MB
    unsigned char*  z8  = y8 + nd;                        // fp8 z          6.4 MB
    int* gcur = (int*)(z8 + (size_t)N_NODES * D_OUT);     // bucket counts
    int* bucketbuf = gcur + 1024;                         // bucket edges   9.6 MB
    unsigned short* Wp1 = (unsigned short*)(bucketbuf + (size_t)NBUCK * BCAP); // 64 KB
    unsigned short* Wp2 = Wp1 + 32768;                    // 32 KB

    hipMemsetAsync(gcur, 0, NBUCK * sizeof(int), stream);

    // 1: multisplit ∪ weight pack
    split_pack<<<NSPL + 24, 256, 0, stream>>>(
        src, dst, gcur, bucketbuf, Ws1, Wn1, Ws2, Wn2, Wp1, Wp2);
    // 2: layer-1 GEMM (ILV1): [xs | y8] = bf16(x) @ [Ws1+b1 | Wn1]
    gemm1<<<GEMM_BLOCKS, 256, 0, stream>>>(x, Wp1, b1, xs, y8);
    // 3: layer-1 bucket aggregation: h = relu(xs + mean(y8[nbrs]))
    bucket_agg<true ><<<NBUCK * 2, 256, 0, stream>>>(y8, gcur, bucketbuf, xs, h);
    // 4: layer-2 GEMM (ILV2; Wp2 K-permuted): [tmp | z8] = h @ [Ws2+b2 | Wn2]
    gemm2<<<GEMM_BLOCKS, 256, 0, stream>>>(h, Wp2, b2, tmp, z8);
    // 5: layer-2 bucket aggregation: out = tmp + mean(z8[nbrs]) (un-permuted)
    bucket_agg<false><<<NBUCK, 256, 0, stream>>>(z8, gcur, bucketbuf, tmp, out);
}

// Round 15
// 272.428 us; speedup vs baseline: 7.4856x; 7.4856x over previous
//
#include <hip/hip_runtime.h>

#define N_NODES 100000
#define N_EDGES 1600000
#define D 128      // D_IN == D_HID
#define D_OUT 64
#define MAXDEG 64  // Poisson(16); max over 100k nodes ~35. 64 = safe pow2.

// Rules learned (r1..r14):
//   r1/r10: csrp scatter = exclusive-owner block + LDS counters
//   r8:     split block count capped by gcur atomic cost
//   r11:    bucketbuf re-scan cost scales with factor (x8 bad; x2 here is cheap)
//   r12:    bucketbuf writes must be dense runs (196 buckets -> 64B runs)
//   r14:    NEVER per-edge LDS float atomics (1181us disaster)
// This round: r9 champion + CSR x2 dloc-split (392 blocks, half the serial
// scatter per block) + sentinel-in-register agg (no csrp zero-fill).
#define NBUCK 196          // buckets of 512 nodes (dense 64B split runs)
#define BSHIFT 9
#define BMASK 511
#define BCAP  12288        // mean 8192 edges/bucket, +45 sigma slack
#define NBLK_SPLIT 500
#define CHUNK 3200         // 500*3200 = 1.6M exact
#define NBLK_PACK 25       // 16 (Wp1) + 8 (Wp2) + 1 (zero pad rows)
#define GEMM_BLOCKS 1563   // ceil(100000/64)
#define CSR_SUB 2          // dloc-range sub-blocks per bucket (256 nodes each)
#define NBLK_CSR (NBUCK * CSR_SUB)   // 392

typedef __attribute__((ext_vector_type(8))) short short8;   // 8 bf16 (4 VGPRs)
typedef __attribute__((ext_vector_type(4))) float floatx4;  // MFMA C/D
typedef __attribute__((ext_vector_type(2))) float floatx2;
typedef __attribute__((ext_vector_type(4))) unsigned uint32x4;

__device__ inline unsigned short f2bf(float f) {   // RNE f32 -> bf16 (cold paths)
    unsigned u = __builtin_bit_cast(unsigned, f);
    u = (u + 0x7fffu + ((u >> 16) & 1u)) >> 16;
    return (unsigned short)u;
}
__device__ inline float bf2f(unsigned u16) {
    return __builtin_bit_cast(float, u16 << 16);
}
// HW packed RNE f32x2 -> bf16x2 (1 instr vs ~8 scalar VALU ops)
__device__ inline unsigned cvt_pk_bf16(float lo, float hi) {
    unsigned r;
    asm("v_cvt_pk_bf16_f32 %0, %1, %2" : "=v"(r) : "v"(lo), "v"(hi));
    return r;
}

// ---- pack W = [Wa | Wb] (N-concat, K=128) into MFMA B-frag order ----
// KPERM: permute K-rows to consume an interleave-stored A (gemm ILV=1 output):
// packed K-position k holds original row ((k&7)<<4)|(k>>3).
template<bool KPERM>
__device__ inline void pack_ncat(const float* __restrict__ Wa, const float* __restrict__ Wb,
                                 int ncA, int ncB, unsigned short* __restrict__ out, int t) {
    int nnt = (ncA + ncB) >> 4;
    int lane = t & 63;
    int nt = (t >> 6) % nnt;
    int kt = t / (64 * nnt);                 // 0..3 (K=128)
    int col = nt * 16 + (lane & 15);
    int k0 = kt * 32 + ((lane >> 4) << 3);
    const float* W = (col < ncA) ? Wa : Wb;
    int nc = (col < ncA) ? ncA : ncB;
    int c  = (col < ncA) ? col : col - ncA;
    unsigned short* dstp = out + (size_t)((kt * nnt + nt) * 64 + lane) * 8;
    #pragma unroll
    for (int j = 0; j < 8; ++j) {
        int k = k0 + j;
        int kr = KPERM ? (((k & 7) << 4) | (k >> 3)) : k;
        dstp[j] = f2bf(W[(size_t)kr * nc + c]);
    }
}

// ------- phase A: multisplit edges into 512-node buckets ∪ weight pack ∪ pad-zero --
__global__ __launch_bounds__(256) void split_pack(
        const int* __restrict__ src, const int* __restrict__ dst,
        int* __restrict__ gcur, int* __restrict__ bucketbuf,
        const float* __restrict__ Ws1, const float* __restrict__ Wn1,
        const float* __restrict__ Ws2, const float* __restrict__ Wn2,
        unsigned short* __restrict__ Wp1, unsigned short* __restrict__ Wp2,
        unsigned char* __restrict__ y8, unsigned char* __restrict__ z8) {
    __shared__ int cnt[NBUCK];
    __shared__ int base_s[NBUCK];
    __shared__ int dstc[CHUNK];    // cache dst chunk: read HBM once, not twice
    const int tid = threadIdx.x;
    const int b = blockIdx.x;
    if (b < NBLK_SPLIT) {
        const int e0 = b * CHUNK;
        for (int i = tid; i < NBUCK; i += 256) cnt[i] = 0;
        __syncthreads();
        for (int i = tid; i < CHUNK; i += 256) {
            int d = __builtin_nontemporal_load(dst + e0 + i);
            dstc[i] = d;
            atomicAdd(&cnt[d >> BSHIFT], 1);
        }
        __syncthreads();
        for (int i = tid; i < NBUCK; i += 256) {
            int c = cnt[i];
            base_s[i] = c ? atomicAdd(&gcur[i], c) : 0;
            cnt[i] = 0;   // reuse as per-block write cursor
        }
        __syncthreads();
        for (int i = tid; i < CHUNK; i += 256) {
            int d = dstc[i];
            int s = __builtin_nontemporal_load(src + e0 + i);
            int bk = d >> BSHIFT;
            int p = base_s[bk] + atomicAdd(&cnt[bk], 1);
            if (p < BCAP)   // statically impossible overflow; safety net
                bucketbuf[bk * BCAP + p] = ((d & BMASK) << 17) | s;
        }
    } else {
        int sub = b - NBLK_SPLIT;
        if (sub < 16)      pack_ncat<false>(Ws1, Wn1, D, D, Wp1, sub * 256 + tid);
        else if (sub < 24) pack_ncat<true >(Ws2, Wn2, D_OUT, D_OUT, Wp2, (sub - 16) * 256 + tid);
        else {
            // zero the sentinel pad rows (agg padding lanes gather from here)
            if (tid < 32)       ((unsigned*)(y8 + (size_t)N_NODES * 128))[tid] = 0;
            else if (tid < 48)  ((unsigned*)(z8 + (size_t)N_NODES * 64))[tid - 32] = 0;
        }
    }
}

// --------------- shared GEMM body: [self+bias | nbr] = A @ [Ws | Wn], K=128 -----
// ILV=1 (layer 1, NTA=NTB=8): store position m*8+nt <- col nt*16+m; one 16B bf16
//   + one 8B fp8 store per row per lane. Wp2 is K-row-permuted to consume it.
// ILV=2 (layer 2, NTA=NTB=4): store position m*4+nt <- col nt*16+m; one 16B f32
//   + one 4B fp8 store. agg_add<L2> un-permutes at its final coalesced write.
template<int NTA, int NTB, bool AF32, int ILV>
__device__ inline void gemm_body(int bid,
        const void* __restrict__ A, const unsigned short* __restrict__ Wp,
        const float* __restrict__ bias, void* __restrict__ OutA,
        unsigned char* __restrict__ OutB, int tid)
{
    const int NT = NTA + NTB;
    const int wave = tid >> 6;
    const int lane = tid & 63;
    const int q = lane >> 4, m = lane & 15;

    int row = bid * 64 + wave * 16 + m;
    int rowc = (row < N_NODES) ? row : (N_NODES - 1);

    floatx4 acc[NT];
    #pragma unroll
    for (int nt = 0; nt < NT; ++nt) acc[nt] = (floatx4){0.f, 0.f, 0.f, 0.f};

    #pragma unroll
    for (int kt = 0; kt < 4; ++kt) {
        short8 af;
        if (AF32) {
            const float* xr = (const float*)A + (size_t)rowc * D + kt * 32 + q * 8;
            float4 f0 = *(const float4*)xr;
            float4 f1 = *(const float4*)(xr + 4);
            uint32x4 t;
            t[0] = cvt_pk_bf16(f0.x, f0.y);
            t[1] = cvt_pk_bf16(f0.z, f0.w);
            t[2] = cvt_pk_bf16(f1.x, f1.y);
            t[3] = cvt_pk_bf16(f1.z, f1.w);
            af = __builtin_bit_cast(short8, t);
        } else {
            af = *(const short8*)((const unsigned short*)A +
                                  (size_t)rowc * D + kt * 32 + q * 8);
        }
        #pragma unroll
        for (int nt = 0; nt < NT; ++nt) {
            short8 bf = *(const short8*)(Wp + (size_t)((kt * NT + nt) * 64 + lane) * 8);
            acc[nt] = __builtin_amdgcn_mfma_f32_16x16x32_bf16(af, bf, acc[nt], 0, 0, 0);
        }
    }

    const int orow_base = bid * 64 + wave * 16 + q * 4;
    if (ILV == 1) {
        float bv[8];
        #pragma unroll
        for (int nt = 0; nt < 8; ++nt) bv[nt] = bias[nt * 16 + m];
        #pragma unroll
        for (int i = 0; i < 4; ++i) {
            int orow = orow_base + i;
            if (orow < N_NODES) {
                uint32x4 pv;
                #pragma unroll
                for (int t = 0; t < 4; ++t)
                    pv[t] = cvt_pk_bf16(acc[2 * t][i]     + bv[2 * t],
                                        acc[2 * t + 1][i] + bv[2 * t + 1]);
                *(uint32x4*)((unsigned short*)OutA + (size_t)orow * 128 + m * 8) = pv;
                int pk0 = __builtin_amdgcn_cvt_pk_fp8_f32(acc[8][i],  acc[9][i],  0,   false);
                pk0     = __builtin_amdgcn_cvt_pk_fp8_f32(acc[10][i], acc[11][i], pk0, true);
                int pk1 = __builtin_amdgcn_cvt_pk_fp8_f32(acc[12][i], acc[13][i], 0,   false);
                pk1     = __builtin_amdgcn_cvt_pk_fp8_f32(acc[14][i], acc[15][i], pk1, true);
                uint2 v8; v8.x = (unsigned)pk0; v8.y = (unsigned)pk1;
                *(uint2*)(OutB + (size_t)orow * 128 + m * 8) = v8;
            }
        }
    } else {  // ILV == 2
        float bv[4];
        #pragma unroll
        for (int nt = 0; nt < 4; ++nt) bv[nt] = bias[nt * 16 + m];
        #pragma unroll
        for (int i = 0; i < 4; ++i) {
            int orow = orow_base + i;
            if (orow < N_NODES) {
                float4 o;
                o.x = acc[0][i] + bv[0]; o.y = acc[1][i] + bv[1];
                o.z = acc[2][i] + bv[2]; o.w = acc[3][i] + bv[3];
                *(float4*)((float*)OutA + (size_t)orow * 64 + m * 4) = o;
                int pk = __builtin_amdgcn_cvt_pk_fp8_f32(acc[4][i], acc[5][i], 0,  false);
                pk     = __builtin_amdgcn_cvt_pk_fp8_f32(acc[6][i], acc[7][i], pk, true);
                *(unsigned*)(OutB + (size_t)orow * 64 + m * 4) = (unsigned)pk;
            }
        }
    }
}

// -------- fused: CSR build (x2 dloc-split) ∪ layer-1 GEMM -----------------------
// CSR blocks FIRST. Sub-block j of bucket b keeps edges with dloc>>8==j:
// exclusive 256-node ownership, LDS counters, half the serial scatter chain of
// r9's monolithic blocks; one extra bucket scan (L2-hot, x2 only).
__global__ __launch_bounds__(256) void gemm1_csr(
        const float* __restrict__ x, const unsigned short* __restrict__ Wp1,
        const float* __restrict__ b1, unsigned short* __restrict__ xs,
        unsigned char* __restrict__ y8,
        const int* __restrict__ gcur, const int* __restrict__ bucketbuf,
        int* __restrict__ dcount, int* __restrict__ csrp)
{
    const int tid = threadIdx.x;
    if (blockIdx.x < NBLK_CSR) {
        __shared__ int lcnt[256];
        const int b   = blockIdx.x >> 1;       // bucket
        const int sub = blockIdx.x & 1;        // dloc range [sub*256, sub*256+256)
        lcnt[tid] = 0;
        __syncthreads();
        int m = gcur[b]; if (m > BCAP) m = BCAP;
        const int* __restrict__ buf = bucketbuf + b * BCAP;
        for (int i = tid; i < m; i += 256) {
            int v = buf[i];
            int dloc = (v >> 17) & BMASK;
            if ((dloc >> 8) == sub) {
                int s = v & 0x1FFFF;
                int node = (b << BSHIFT) + dloc;
                int slot = atomicAdd(&lcnt[dloc & 255], 1);
                if (slot < MAXDEG && node < N_NODES)
                    csrp[((size_t)node << 6) + slot] = s;
            }
        }
        __syncthreads();
        {
            int node = (b << BSHIFT) + (sub << 8) + tid;
            if (node < N_NODES) {
                int c = lcnt[tid];
                dcount[node] = (c > MAXDEG) ? MAXDEG : c;
            }
        }
    } else {
        gemm_body<8, 8, true, 1>(blockIdx.x - NBLK_CSR, x, Wp1, b1, xs, y8, tid);
    }
}

// --------------------- layer-2 GEMM (standalone launch) -------------------------
__global__ __launch_bounds__(256) void gemm2(
        const unsigned short* __restrict__ h, const unsigned short* __restrict__ Wp2,
        const float* __restrict__ b2, float* __restrict__ tmp,
        unsigned char* __restrict__ z8)
{
    gemm_body<4, 4, false, 2>(blockIdx.x, h, Wp2, b2, tmp, z8, threadIdx.x);
}

// ---------- mean-agg + self-add: one wave per node, 4B/lane dword gathers -------
// csrp read ONLY for lanes < dg (1 cache line typical); padding lanes get the
// sentinel N_NODES in-register -> no zero-fill pass. L1: 32 lanes/edge, fold =
// ONE shfl step. L2: 16 lanes/edge, fold = two; inputs pi2-permuted, final
// store un-permutes (4 coalesced 64B runs).
template<bool L1>
__global__ __launch_bounds__(256) void agg_add(
        const unsigned char* __restrict__ feat, const int* __restrict__ csrp,
        const int* __restrict__ dcount, const void* __restrict__ self,
        void* __restrict__ out)
{
    const int LPE = L1 ? 32 : 16;      // lanes per edge (4B/lane)
    const int EPG = 64 / LPE;          // edges per load-group: 2 (L1), 4 (L2)
    const int FSH = L1 ? 7 : 6;        // log2(row bytes)
    const int NC  = L1 ? 128 : 64;     // columns

    int w = (blockIdx.x * 256 + threadIdx.x) >> 6;
    int lane = threadIdx.x & 63;
    if (w >= N_NODES) return;
    int dg = __builtin_amdgcn_readfirstlane(dcount[w]);
    const int g = lane / LPE;          // edge slot within group
    const int l = lane % LPE;          // dword chunk (4 columns)
    int idxv = N_NODES;                // sentinel -> zeroed pad row
    if (lane < dg) idxv = csrp[((size_t)w << 6) + lane];

    floatx2 ac0 = (floatx2){0.f, 0.f};
    floatx2 ac1 = (floatx2){0.f, 0.f};
    for (int j = 0; j < dg; j += 16) {
        #pragma unroll
        for (int u = 0; u < 16 / EPG; ++u) {
            int s = __shfl(idxv, j + u * EPG + g);
            unsigned v = *(const unsigned*)(feat + ((size_t)s << FSH) + (l << 2));
            ac0 += __builtin_amdgcn_cvt_pk_f32_fp8(v, false);
            ac1 += __builtin_amdgcn_cvt_pk_f32_fp8(v, true);
        }
    }
    // fold edge-slot groups (lanes sharing l)
    #pragma unroll
    for (int delta = 32; delta >= LPE; delta >>= 1) {
        ac0.x += __shfl_down(ac0.x, delta); ac0.y += __shfl_down(ac0.y, delta);
        ac1.x += __shfl_down(ac1.x, delta); ac1.y += __shfl_down(ac1.y, delta);
    }
    if (g == 0) {                      // lanes 0..LPE-1 hold 4-col sums
        float invd = (dg > 0) ? 1.0f / (float)dg : 1.0f;
        if (L1) {                      // self bf16, out bf16 + ReLU (positional)
            uint2 sv = *(const uint2*)((const unsigned short*)self + (size_t)w * NC + l * 4);
            float h0 = bf2f(sv.x & 0xffffu)  + ac0.x * invd;
            float h1 = bf2f(sv.x >> 16)      + ac0.y * invd;
            float h2 = bf2f(sv.y & 0xffffu)  + ac1.x * invd;
            float h3 = bf2f(sv.y >> 16)      + ac1.y * invd;
            h0 = fmaxf(h0, 0.f); h1 = fmaxf(h1, 0.f);
            h2 = fmaxf(h2, 0.f); h3 = fmaxf(h3, 0.f);
            uint2 pv;
            pv.x = cvt_pk_bf16(h0, h1);
            pv.y = cvt_pk_bf16(h2, h3);
            *(uint2*)((unsigned short*)out + (size_t)w * NC + l * 4) = pv;
        } else {                       // self f32 (pi2), out f32 (identity)
            const float* sp = (const float*)self + (size_t)w * NC + l * 4;
            float4 s0 = *(const float4*)sp;
            float v0 = s0.x + ac0.x * invd;   // col l
            float v1 = s0.y + ac0.y * invd;   // col 16+l
            float v2 = s0.z + ac1.x * invd;   // col 32+l
            float v3 = s0.w + ac1.y * invd;   // col 48+l
            float* op = (float*)out + (size_t)w * NC;
            op[l]      = v0;
            op[16 + l] = v1;
            op[32 + l] = v2;
            op[48 + l] = v3;
        }
    }
}

extern "C" void kernel_launch(void* const* d_in, const int* in_sizes, int n_in,
                              void* d_out, int out_size, void* d_ws, size_t ws_size,
                              hipStream_t stream) {
    const float* x   = (const float*)d_in[0];
    const int*   src = (const int*)d_in[1];
    const int*   dst = (const int*)d_in[2];
    const float* Ws1 = (const float*)d_in[3];
    const float* Wn1 = (const float*)d_in[4];
    const float* b1  = (const float*)d_in[5];
    const float* Ws2 = (const float*)d_in[6];
    const float* Wn2 = (const float*)d_in[7];
    const float* b2  = (const float*)d_in[8];
    float* out = (float*)d_out;

    const size_t nd = (size_t)N_NODES * D;   // 12.8M elements
    unsigned short* h   = (unsigned short*)d_ws;          // bf16 hidden   25.6 MB
    unsigned short* xs  = h + nd;                         // bf16 self (L1) 25.6 MB
    float*          tmp = (float*)xs;                     // f32 self (L2), aliased
    unsigned char*  y8  = (unsigned char*)(xs + nd);      // fp8 y + pad   12.9 MB
    unsigned char*  z8  = y8 + (size_t)(N_NODES + 1) * D; // fp8 z + pad    6.5 MB
    int* dcount = (int*)(z8 + (size_t)(N_NODES + 1) * D_OUT);
    int* csrp   = dcount + N_NODES;                       // padded CSR    25.6 MB
    int* gcur   = csrp + (size_t)N_NODES * MAXDEG;        // (pad to 1024)
    int* bucketbuf = gcur + 1024;                         // bucket edges   9.6 MB
    unsigned short* Wp1 = (unsigned short*)(bucketbuf + (size_t)NBUCK * BCAP); // 64 KB
    unsigned short* Wp2 = Wp1 + 32768;                    // 32 KB

    hipMemsetAsync(gcur, 0, NBUCK * sizeof(int), stream);

    split_pack<<<NBLK_SPLIT + NBLK_PACK, 256, 0, stream>>>(
        src, dst, gcur, bucketbuf, Ws1, Wn1, Ws2, Wn2, Wp1, Wp2, y8, z8);

    const int agg_blocks = (N_NODES * 64 + 255) / 256;    // 25000

    // CSR build (392 dloc-split blocks, first) fused with layer-1 GEMM (ILV1)
    gemm1_csr<<<NBLK_CSR + GEMM_BLOCKS, 256, 0, stream>>>(
        x, Wp1, b1, xs, y8, gcur, bucketbuf, dcount, csrp);
    agg_add<true ><<<agg_blocks, 256, 0, stream>>>(y8, csrp, dcount, xs, h);
    // layer 2 (ILV2; Wp2 K-rows permuted to consume interleaved h)
    gemm2<<<GEMM_BLOCKS, 256, 0, stream>>>(h, Wp2, b2, tmp, z8);
    agg_add<false><<<agg_blocks, 256, 0, stream>>>(z8, csrp, dcount, tmp, out);
}

// Round 17
// 270.352 us; speedup vs baseline: 7.5431x; 1.0077x over previous
//
#include <hip/hip_runtime.h>

#define N_NODES 100000
#define N_EDGES 1600000
#define D 128      // D_IN == D_HID
#define D_OUT 64
#define MAXDEG 64  // Poisson(16); max over 100k nodes ~35. 64 = safe pow2.

// Rules learned (r1..r15):
//   r1/r10: csrp scatter = exclusive-owner block + LDS counters
//   r8:     split block count capped by gcur atomic cost
//   r11:    bucketbuf re-scan cost scales with factor
//   r12:    bucketbuf writes must be dense runs
//   r14:    NEVER per-edge LDS float atomics
//   r15:    CSR split-factor is null -> gemm half of gemm1_csr is the wall
// This round (r16 resubmit — r16 bench was an infra flake): M-block x2 in both
// gemms (each wave = two 16-row groups sharing every B fragment: MFMA:B-load
// 1:1 -> 2:1) to attack the B-load latency that pins MfmaUtil at 4%.
#define NBUCK 196          // buckets of 512 nodes (dense 64B split runs)
#define BSHIFT 9
#define BMASK 511
#define BCAP  12288        // mean 8192 edges/bucket, +45 sigma slack
#define NBLK_SPLIT 500
#define CHUNK 3200         // 500*3200 = 1.6M exact
#define NBLK_PACK 25       // 16 (Wp1) + 8 (Wp2) + 1 (zero pad rows)
#define GEMM_MBLOCKS 782   // ceil(100000/128) — 128 rows per block now
#define CSR_SUB 2          // dloc-range sub-blocks per bucket (256 nodes each)
#define NBLK_CSR (NBUCK * CSR_SUB)   // 392

typedef __attribute__((ext_vector_type(8))) short short8;   // 8 bf16 (4 VGPRs)
typedef __attribute__((ext_vector_type(4))) float floatx4;  // MFMA C/D
typedef __attribute__((ext_vector_type(2))) float floatx2;
typedef __attribute__((ext_vector_type(4))) unsigned uint32x4;

__device__ inline unsigned short f2bf(float f) {   // RNE f32 -> bf16 (cold paths)
    unsigned u = __builtin_bit_cast(unsigned, f);
    u = (u + 0x7fffu + ((u >> 16) & 1u)) >> 16;
    return (unsigned short)u;
}
__device__ inline float bf2f(unsigned u16) {
    return __builtin_bit_cast(float, u16 << 16);
}
// HW packed RNE f32x2 -> bf16x2 (1 instr vs ~8 scalar VALU ops)
__device__ inline unsigned cvt_pk_bf16(float lo, float hi) {
    unsigned r;
    asm("v_cvt_pk_bf16_f32 %0, %1, %2" : "=v"(r) : "v"(lo), "v"(hi));
    return r;
}

// ---- pack W = [Wa | Wb] (N-concat, K=128) into MFMA B-frag order ----
// KPERM: permute K-rows to consume an interleave-stored A (gemm ILV=1 output):
// packed K-position k holds original row ((k&7)<<4)|(k>>3).
template<bool KPERM>
__device__ inline void pack_ncat(const float* __restrict__ Wa, const float* __restrict__ Wb,
                                 int ncA, int ncB, unsigned short* __restrict__ out, int t) {
    int nnt = (ncA + ncB) >> 4;
    int lane = t & 63;
    int nt = (t >> 6) % nnt;
    int kt = t / (64 * nnt);                 // 0..3 (K=128)
    int col = nt * 16 + (lane & 15);
    int k0 = kt * 32 + ((lane >> 4) << 3);
    const float* W = (col < ncA) ? Wa : Wb;
    int nc = (col < ncA) ? ncA : ncB;
    int c  = (col < ncA) ? col : col - ncA;
    unsigned short* dstp = out + (size_t)((kt * nnt + nt) * 64 + lane) * 8;
    #pragma unroll
    for (int j = 0; j < 8; ++j) {
        int k = k0 + j;
        int kr = KPERM ? (((k & 7) << 4) | (k >> 3)) : k;
        dstp[j] = f2bf(W[(size_t)kr * nc + c]);
    }
}

// ------- phase A: multisplit edges into 512-node buckets ∪ weight pack ∪ pad-zero --
__global__ __launch_bounds__(256) void split_pack(
        const int* __restrict__ src, const int* __restrict__ dst,
        int* __restrict__ gcur, int* __restrict__ bucketbuf,
        const float* __restrict__ Ws1, const float* __restrict__ Wn1,
        const float* __restrict__ Ws2, const float* __restrict__ Wn2,
        unsigned short* __restrict__ Wp1, unsigned short* __restrict__ Wp2,
        unsigned char* __restrict__ y8, unsigned char* __restrict__ z8) {
    __shared__ int cnt[NBUCK];
    __shared__ int base_s[NBUCK];
    __shared__ int dstc[CHUNK];    // cache dst chunk: read HBM once, not twice
    const int tid = threadIdx.x;
    const int b = blockIdx.x;
    if (b < NBLK_SPLIT) {
        const int e0 = b * CHUNK;
        for (int i = tid; i < NBUCK; i += 256) cnt[i] = 0;
        __syncthreads();
        for (int i = tid; i < CHUNK; i += 256) {
            int d = __builtin_nontemporal_load(dst + e0 + i);
            dstc[i] = d;
            atomicAdd(&cnt[d >> BSHIFT], 1);
        }
        __syncthreads();
        for (int i = tid; i < NBUCK; i += 256) {
            int c = cnt[i];
            base_s[i] = c ? atomicAdd(&gcur[i], c) : 0;
            cnt[i] = 0;   // reuse as per-block write cursor
        }
        __syncthreads();
        for (int i = tid; i < CHUNK; i += 256) {
            int d = dstc[i];
            int s = __builtin_nontemporal_load(src + e0 + i);
            int bk = d >> BSHIFT;
            int p = base_s[bk] + atomicAdd(&cnt[bk], 1);
            if (p < BCAP)   // statically impossible overflow; safety net
                bucketbuf[bk * BCAP + p] = ((d & BMASK) << 17) | s;
        }
    } else {
        int sub = b - NBLK_SPLIT;
        if (sub < 16)      pack_ncat<false>(Ws1, Wn1, D, D, Wp1, sub * 256 + tid);
        else if (sub < 24) pack_ncat<true >(Ws2, Wn2, D_OUT, D_OUT, Wp2, (sub - 16) * 256 + tid);
        else {
            // zero the sentinel pad rows (agg padding lanes gather from here)
            if (tid < 32)       ((unsigned*)(y8 + (size_t)N_NODES * 128))[tid] = 0;
            else if (tid < 48)  ((unsigned*)(z8 + (size_t)N_NODES * 64))[tid - 32] = 0;
        }
    }
}

// --------- shared GEMM body, M-blocked x2: each wave = 2x16 rows, shared B -----
// Block covers 128 rows (4 waves x 32). Both row groups consume the SAME bf
// fragment -> B-load count per MFMA halves (the r15-diagnosed latency wall).
// ILV=1 (layer 1, NTA=NTB=8): store position m*8+nt <- col nt*16+m.
// ILV=2 (layer 2, NTA=NTB=4): store position m*4+nt <- col nt*16+m;
//   agg_add<L2> un-permutes at its final coalesced write.
template<int NTA, int NTB, bool AF32, int ILV>
__device__ inline void gemm_body(int bid,
        const void* __restrict__ A, const unsigned short* __restrict__ Wp,
        const float* __restrict__ bias, void* __restrict__ OutA,
        unsigned char* __restrict__ OutB, int tid)
{
    const int NT = NTA + NTB;
    const int wave = tid >> 6;
    const int lane = tid & 63;
    const int q = lane >> 4, m = lane & 15;

    const int rowb = bid * 128 + wave * 32 + m;
    const int rowc0 = (rowb      < N_NODES) ? rowb      : (N_NODES - 1);
    const int rowc1 = (rowb + 16 < N_NODES) ? rowb + 16 : (N_NODES - 1);

    floatx4 acc[2][NT];
    #pragma unroll
    for (int g = 0; g < 2; ++g)
        #pragma unroll
        for (int nt = 0; nt < NT; ++nt) acc[g][nt] = (floatx4){0.f, 0.f, 0.f, 0.f};

    #pragma unroll
    for (int kt = 0; kt < 4; ++kt) {
        short8 af0, af1;
        if (AF32) {
            const float* xr0 = (const float*)A + (size_t)rowc0 * D + kt * 32 + q * 8;
            const float* xr1 = (const float*)A + (size_t)rowc1 * D + kt * 32 + q * 8;
            float4 a0 = *(const float4*)xr0, a1 = *(const float4*)(xr0 + 4);
            float4 c0 = *(const float4*)xr1, c1 = *(const float4*)(xr1 + 4);
            uint32x4 t0, t1;
            t0[0] = cvt_pk_bf16(a0.x, a0.y); t0[1] = cvt_pk_bf16(a0.z, a0.w);
            t0[2] = cvt_pk_bf16(a1.x, a1.y); t0[3] = cvt_pk_bf16(a1.z, a1.w);
            t1[0] = cvt_pk_bf16(c0.x, c0.y); t1[1] = cvt_pk_bf16(c0.z, c0.w);
            t1[2] = cvt_pk_bf16(c1.x, c1.y); t1[3] = cvt_pk_bf16(c1.z, c1.w);
            af0 = __builtin_bit_cast(short8, t0);
            af1 = __builtin_bit_cast(short8, t1);
        } else {
            af0 = *(const short8*)((const unsigned short*)A +
                                   (size_t)rowc0 * D + kt * 32 + q * 8);
            af1 = *(const short8*)((const unsigned short*)A +
                                   (size_t)rowc1 * D + kt * 32 + q * 8);
        }
        #pragma unroll
        for (int nt = 0; nt < NT; ++nt) {
            short8 bf = *(const short8*)(Wp + (size_t)((kt * NT + nt) * 64 + lane) * 8);
            acc[0][nt] = __builtin_amdgcn_mfma_f32_16x16x32_bf16(af0, bf, acc[0][nt], 0, 0, 0);
            acc[1][nt] = __builtin_amdgcn_mfma_f32_16x16x32_bf16(af1, bf, acc[1][nt], 0, 0, 0);
        }
    }

    #pragma unroll
    for (int g = 0; g < 2; ++g) {
        const int orow_base = bid * 128 + wave * 32 + g * 16 + q * 4;
        if (ILV == 1) {
            float bv[8];
            #pragma unroll
            for (int nt = 0; nt < 8; ++nt) bv[nt] = bias[nt * 16 + m];
            #pragma unroll
            for (int i = 0; i < 4; ++i) {
                int orow = orow_base + i;
                if (orow < N_NODES) {
                    uint32x4 pv;
                    #pragma unroll
                    for (int t = 0; t < 4; ++t)
                        pv[t] = cvt_pk_bf16(acc[g][2 * t][i]     + bv[2 * t],
                                            acc[g][2 * t + 1][i] + bv[2 * t + 1]);
                    *(uint32x4*)((unsigned short*)OutA + (size_t)orow * 128 + m * 8) = pv;
                    int pk0 = __builtin_amdgcn_cvt_pk_fp8_f32(acc[g][8][i],  acc[g][9][i],  0,   false);
                    pk0     = __builtin_amdgcn_cvt_pk_fp8_f32(acc[g][10][i], acc[g][11][i], pk0, true);
                    int pk1 = __builtin_amdgcn_cvt_pk_fp8_f32(acc[g][12][i], acc[g][13][i], 0,   false);
                    pk1     = __builtin_amdgcn_cvt_pk_fp8_f32(acc[g][14][i], acc[g][15][i], pk1, true);
                    uint2 v8; v8.x = (unsigned)pk0; v8.y = (unsigned)pk1;
                    *(uint2*)(OutB + (size_t)orow * 128 + m * 8) = v8;
                }
            }
        } else {  // ILV == 2
            float bv[4];
            #pragma unroll
            for (int nt = 0; nt < 4; ++nt) bv[nt] = bias[nt * 16 + m];
            #pragma unroll
            for (int i = 0; i < 4; ++i) {
                int orow = orow_base + i;
                if (orow < N_NODES) {
                    float4 o;
                    o.x = acc[g][0][i] + bv[0]; o.y = acc[g][1][i] + bv[1];
                    o.z = acc[g][2][i] + bv[2]; o.w = acc[g][3][i] + bv[3];
                    *(float4*)((float*)OutA + (size_t)orow * 64 + m * 4) = o;
                    int pk = __builtin_amdgcn_cvt_pk_fp8_f32(acc[g][4][i], acc[g][5][i], 0,  false);
                    pk     = __builtin_amdgcn_cvt_pk_fp8_f32(acc[g][6][i], acc[g][7][i], pk, true);
                    *(unsigned*)(OutB + (size_t)orow * 64 + m * 4) = (unsigned)pk;
                }
            }
        }
    }
}

// -------- fused: CSR build (x2 dloc-split) ∪ layer-1 GEMM (M-blocked) -----------
__global__ __launch_bounds__(256) void gemm1_csr(
        const float* __restrict__ x, const unsigned short* __restrict__ Wp1,
        const float* __restrict__ b1, unsigned short* __restrict__ xs,
        unsigned char* __restrict__ y8,
        const int* __restrict__ gcur, const int* __restrict__ bucketbuf,
        int* __restrict__ dcount, int* __restrict__ csrp)
{
    const int tid = threadIdx.x;
    if (blockIdx.x < NBLK_CSR) {
        __shared__ int lcnt[256];
        const int b   = blockIdx.x >> 1;       // bucket
        const int sub = blockIdx.x & 1;        // dloc range [sub*256, sub*256+256)
        lcnt[tid] = 0;
        __syncthreads();
        int m = gcur[b]; if (m > BCAP) m = BCAP;
        const int* __restrict__ buf = bucketbuf + b * BCAP;
        for (int i = tid; i < m; i += 256) {
            int v = buf[i];
            int dloc = (v >> 17) & BMASK;
            if ((dloc >> 8) == sub) {
                int s = v & 0x1FFFF;
                int node = (b << BSHIFT) + dloc;
                int slot = atomicAdd(&lcnt[dloc & 255], 1);
                if (slot < MAXDEG && node < N_NODES)
                    csrp[((size_t)node << 6) + slot] = s;
            }
        }
        __syncthreads();
        {
            int node = (b << BSHIFT) + (sub << 8) + tid;
            if (node < N_NODES) {
                int c = lcnt[tid];
                dcount[node] = (c > MAXDEG) ? MAXDEG : c;
            }
        }
    } else {
        gemm_body<8, 8, true, 1>(blockIdx.x - NBLK_CSR, x, Wp1, b1, xs, y8, tid);
    }
}

// --------------------- layer-2 GEMM (standalone launch) -------------------------
__global__ __launch_bounds__(256) void gemm2(
        const unsigned short* __restrict__ h, const unsigned short* __restrict__ Wp2,
        const float* __restrict__ b2, float* __restrict__ tmp,
        unsigned char* __restrict__ z8)
{
    gemm_body<4, 4, false, 2>(blockIdx.x, h, Wp2, b2, tmp, z8, threadIdx.x);
}

// ---------- mean-agg + self-add: one wave per node, 4B/lane dword gathers -------
// csrp read ONLY for lanes < dg (1 cache line typical); padding lanes get the
// sentinel N_NODES in-register -> no zero-fill pass. L1: 32 lanes/edge, fold =
// ONE shfl step. L2: 16 lanes/edge, fold = two; inputs pi2-permuted, final
// store un-permutes (4 coalesced 64B runs).
template<bool L1>
__global__ __launch_bounds__(256) void agg_add(
        const unsigned char* __restrict__ feat, const int* __restrict__ csrp,
        const int* __restrict__ dcount, const void* __restrict__ self,
        void* __restrict__ out)
{
    const int LPE = L1 ? 32 : 16;      // lanes per edge (4B/lane)
    const int EPG = 64 / LPE;          // edges per load-group: 2 (L1), 4 (L2)
    const int FSH = L1 ? 7 : 6;        // log2(row bytes)
    const int NC  = L1 ? 128 : 64;     // columns

    int w = (blockIdx.x * 256 + threadIdx.x) >> 6;
    int lane = threadIdx.x & 63;
    if (w >= N_NODES) return;
    int dg = __builtin_amdgcn_readfirstlane(dcount[w]);
    const int g = lane / LPE;          // edge slot within group
    const int l = lane % LPE;          // dword chunk (4 columns)
    int idxv = N_NODES;                // sentinel -> zeroed pad row
    if (lane < dg) idxv = csrp[((size_t)w << 6) + lane];

    floatx2 ac0 = (floatx2){0.f, 0.f};
    floatx2 ac1 = (floatx2){0.f, 0.f};
    for (int j = 0; j < dg; j += 16) {
        #pragma unroll
        for (int u = 0; u < 16 / EPG; ++u) {
            int s = __shfl(idxv, j + u * EPG + g);
            unsigned v = *(const unsigned*)(feat + ((size_t)s << FSH) + (l << 2));
            ac0 += __builtin_amdgcn_cvt_pk_f32_fp8(v, false);
            ac1 += __builtin_amdgcn_cvt_pk_f32_fp8(v, true);
        }
    }
    // fold edge-slot groups (lanes sharing l)
    #pragma unroll
    for (int delta = 32; delta >= LPE; delta >>= 1) {
        ac0.x += __shfl_down(ac0.x, delta); ac0.y += __shfl_down(ac0.y, delta);
        ac1.x += __shfl_down(ac1.x, delta); ac1.y += __shfl_down(ac1.y, delta);
    }
    if (g == 0) {                      // lanes 0..LPE-1 hold 4-col sums
        float invd = (dg > 0) ? 1.0f / (float)dg : 1.0f;
        if (L1) {                      // self bf16, out bf16 + ReLU (positional)
            uint2 sv = *(const uint2*)((const unsigned short*)self + (size_t)w * NC + l * 4);
            float h0 = bf2f(sv.x & 0xffffu)  + ac0.x * invd;
            float h1 = bf2f(sv.x >> 16)      + ac0.y * invd;
            float h2 = bf2f(sv.y & 0xffffu)  + ac1.x * invd;
            float h3 = bf2f(sv.y >> 16)      + ac1.y * invd;
            h0 = fmaxf(h0, 0.f); h1 = fmaxf(h1, 0.f);
            h2 = fmaxf(h2, 0.f); h3 = fmaxf(h3, 0.f);
            uint2 pv;
            pv.x = cvt_pk_bf16(h0, h1);
            pv.y = cvt_pk_bf16(h2, h3);
            *(uint2*)((unsigned short*)out + (size_t)w * NC + l * 4) = pv;
        } else {                       // self f32 (pi2), out f32 (identity)
            const float* sp = (const float*)self + (size_t)w * NC + l * 4;
            float4 s0 = *(const float4*)sp;
            float v0 = s0.x + ac0.x * invd;   // col l
            float v1 = s0.y + ac0.y * invd;   // col 16+l
            float v2 = s0.z + ac1.x * invd;   // col 32+l
            float v3 = s0.w + ac1.y * invd;   // col 48+l
            float* op = (float*)out + (size_t)w * NC;
            op[l]      = v0;
            op[16 + l] = v1;
            op[32 + l] = v2;
            op[48 + l] = v3;
        }
    }
}

extern "C" void kernel_launch(void* const* d_in, const int* in_sizes, int n_in,
                              void* d_out, int out_size, void* d_ws, size_t ws_size,
                              hipStream_t stream) {
    const float* x   = (const float*)d_in[0];
    const int*   src = (const int*)d_in[1];
    const int*   dst = (const int*)d_in[2];
    const float* Ws1 = (const float*)d_in[3];
    const float* Wn1 = (const float*)d_in[4];
    const float* b1  = (const float*)d_in[5];
    const float* Ws2 = (const float*)d_in[6];
    const float* Wn2 = (const float*)d_in[7];
    const float* b2  = (const float*)d_in[8];
    float* out = (float*)d_out;

    const size_t nd = (size_t)N_NODES * D;   // 12.8M elements
    unsigned short* h   = (unsigned short*)d_ws;          // bf16 hidden   25.6 MB
    unsigned short* xs  = h + nd;                         // bf16 self (L1) 25.6 MB
    float*          tmp = (float*)xs;                     // f32 self (L2), aliased
    unsigned char*  y8  = (unsigned char*)(xs + nd);      // fp8 y + pad   12.9 MB
    unsigned char*  z8  = y8 + (size_t)(N_NODES + 1) * D; // fp8 z + pad    6.5 MB
    int* dcount = (int*)(z8 + (size_t)(N_NODES + 1) * D_OUT);
    int* csrp   = dcount + N_NODES;                       // padded CSR    25.6 MB
    int* gcur   = csrp + (size_t)N_NODES * MAXDEG;        // (pad to 1024)
    int* bucketbuf = gcur + 1024;                         // bucket edges   9.6 MB
    unsigned short* Wp1 = (unsigned short*)(bucketbuf + (size_t)NBUCK * BCAP); // 64 KB
    unsigned short* Wp2 = Wp1 + 32768;                    // 32 KB

    hipMemsetAsync(gcur, 0, NBUCK * sizeof(int), stream);

    split_pack<<<NBLK_SPLIT + NBLK_PACK, 256, 0, stream>>>(
        src, dst, gcur, bucketbuf, Ws1, Wn1, Ws2, Wn2, Wp1, Wp2, y8, z8);

    const int agg_blocks = (N_NODES * 64 + 255) / 256;    // 25000

    // CSR build (392 dloc-split blocks, first) fused with layer-1 GEMM (M-blocked)
    gemm1_csr<<<NBLK_CSR + GEMM_MBLOCKS, 256, 0, stream>>>(
        x, Wp1, b1, xs, y8, gcur, bucketbuf, dcount, csrp);
    agg_add<true ><<<agg_blocks, 256, 0, stream>>>(y8, csrp, dcount, xs, h);
    // layer 2 (ILV2; Wp2 K-rows permuted to consume interleaved h, M-blocked)
    gemm2<<<GEMM_MBLOCKS, 256, 0, stream>>>(h, Wp2, b2, tmp, z8);
    agg_add<false><<<agg_blocks, 256, 0, stream>>>(z8, csrp, dcount, tmp, out);
}